// Round 3
// baseline (57.945 us; speedup 1.0000x reference)
//
#include <hip/hip_runtime.h>
#include <hip/hip_bf16.h>

#define B 8
#define N 4096
#define BN (B * N)          // 32768 nodes total
#define NBLK 512            // k_min grid size

// ---- order-preserving float <-> uint key (works for negative floats) ----
__device__ __forceinline__ unsigned enc_f(float f) {
    unsigned u = __float_as_uint(f);
    return u ^ (unsigned)(((int)u >> 31) | 0x80000000);
}
__device__ __forceinline__ float dec_f(unsigned k) {
    unsigned u = (k & 0x80000000u) ? (k ^ 0x80000000u) : ~k;
    return __uint_as_float(u);
}
#define ENC_INF 0xFF800000u   // enc_f(+inf)

// ---------------- init: wmin=enc(inf), transformed candidates, counter=0 ----
// cand4[i] = (-2x, -2y, -2z, x^2+y^2+z^2) so that
// d^2(q, c_i) = |q|^2 + fma(qx,cand.x, fma(qy,cand.y, fma(qz,cand.z, cand.w)))
__global__ __launch_bounds__(256) void k_init(const float* __restrict__ c,
                                              unsigned* __restrict__ wmin,
                                              float4* __restrict__ cand4,
                                              unsigned* __restrict__ counter) {
    int i = blockIdx.x * 256 + threadIdx.x;   // grid covers exactly BN
    float x = c[3 * i], y = c[3 * i + 1], z = c[3 * i + 2];
    wmin[i]  = ENC_INF;
    cand4[i] = make_float4(-2.0f * x, -2.0f * y, -2.0f * z,
                           x * x + y * y + z * z);
    if (i == 0) *counter = 0u;
}

// ---------------- main: min over v = d^2 - |q|^2, fused final loss ----------
// Block (256 thr = 4 waves): 256 queries x 1024 candidates.
// Wave w: same 256 queries, its own 256-candidate chunk via SCALAR loads.
// Thread: 4 consecutive queries in registers; 3 FMA + shared min3 per pair.
__global__ __launch_bounds__(256) void k_min(const float* __restrict__ c,
                                             const float4* __restrict__ cand4,
                                             unsigned* __restrict__ wmin,
                                             unsigned* __restrict__ counter,
                                             float* __restrict__ out) {
    int blk = blockIdx.x;
    int cc  = blk & 3;          // candidate super-chunk (1024)
    int qc  = (blk >> 2) & 15;  // query chunk (256)
    int b   = blk >> 6;         // batch

    int w = __builtin_amdgcn_readfirstlane((int)(threadIdx.x >> 6));
    int l = threadIdx.x & 63;

    const float* cb = c + (size_t)b * N * 3;
    int qbase  = qc * 256;
    int cstart = cc * 1024 + w * 256;

    // this thread's 4 queries (48 contiguous bytes)
    const float4* q4p = (const float4*)(cb + 3 * qbase + 12 * l);
    float4 a0 = q4p[0], a1 = q4p[1], a2 = q4p[2];
    float qx0 = a0.x, qy0 = a0.y, qz0 = a0.z;
    float qx1 = a0.w, qy1 = a1.x, qz1 = a1.y;
    float qx2 = a1.z, qy2 = a1.w, qz2 = a2.x;
    float qx3 = a2.y, qy3 = a2.z, qz3 = a2.w;

    const float INF = __uint_as_float(0x7F800000u);
    float m0 = INF, m1 = INF, m2 = INF, m3 = INF;

    const float4* cp = cand4 + (size_t)b * N + cstart;  // wave-uniform -> s_load

    if (cstart != qbase) {
        // off-diagonal: no self possible
        #pragma unroll 4
        for (int k = 0; k < 256; k += 2) {
            float4 u = cp[k], v = cp[k + 1];
            float va0 = fmaf(qx0, u.x, fmaf(qy0, u.y, fmaf(qz0, u.z, u.w)));
            float vb0 = fmaf(qx0, v.x, fmaf(qy0, v.y, fmaf(qz0, v.z, v.w)));
            float va1 = fmaf(qx1, u.x, fmaf(qy1, u.y, fmaf(qz1, u.z, u.w)));
            float vb1 = fmaf(qx1, v.x, fmaf(qy1, v.y, fmaf(qz1, v.z, v.w)));
            float va2 = fmaf(qx2, u.x, fmaf(qy2, u.y, fmaf(qz2, u.z, u.w)));
            float vb2 = fmaf(qx2, v.x, fmaf(qy2, v.y, fmaf(qz2, v.z, v.w)));
            float va3 = fmaf(qx3, u.x, fmaf(qy3, u.y, fmaf(qz3, u.z, u.w)));
            float vb3 = fmaf(qx3, v.x, fmaf(qy3, v.y, fmaf(qz3, v.z, v.w)));
            m0 = fminf(fminf(m0, va0), vb0);   // -> v_min3_f32
            m1 = fminf(fminf(m1, va1), vb1);
            m2 = fminf(fminf(m2, va2), vb2);
            m3 = fminf(fminf(m3, va3), vb3);
        }
    } else {
        // diagonal chunk: query j's relative self index is 4*l+j
        int s = l << 2;
        #pragma unroll 4
        for (int k = 0; k < 256; ++k) {
            float4 u = cp[k];
            float v0 = fmaf(qx0, u.x, fmaf(qy0, u.y, fmaf(qz0, u.z, u.w)));
            float v1 = fmaf(qx1, u.x, fmaf(qy1, u.y, fmaf(qz1, u.z, u.w)));
            float v2 = fmaf(qx2, u.x, fmaf(qy2, u.y, fmaf(qz2, u.z, u.w)));
            float v3 = fmaf(qx3, u.x, fmaf(qy3, u.y, fmaf(qz3, u.z, u.w)));
            v0 = (k == s + 0) ? INF : v0;
            v1 = (k == s + 1) ? INF : v1;
            v2 = (k == s + 2) ? INF : v2;
            v3 = (k == s + 3) ? INF : v3;
            m0 = fminf(m0, v0);
            m1 = fminf(m1, v1);
            m2 = fminf(m2, v2);
            m3 = fminf(m3, v3);
        }
    }

    // cross-wave min reduce in LDS
    __shared__ float4 shm[3][64];
    __shared__ int islast;
    if (w) shm[w - 1][l] = make_float4(m0, m1, m2, m3);
    __syncthreads();
    if (w == 0) {
        #pragma unroll
        for (int ww = 0; ww < 3; ++ww) {
            float4 v = shm[ww][l];
            m0 = fminf(m0, v.x); m1 = fminf(m1, v.y);
            m2 = fminf(m2, v.z); m3 = fminf(m3, v.w);
        }
        unsigned* wp = wmin + b * N + qbase + (l << 2);
        atomicMin(wp + 0, enc_f(m0));
        atomicMin(wp + 1, enc_f(m1));
        atomicMin(wp + 2, enc_f(m2));
        atomicMin(wp + 3, enc_f(m3));
        if (l == 0) {
            __threadfence();                         // release our mins
            unsigned old = atomicAdd(counter, 1u);
            islast = (old == NBLK - 1);
        }
    }
    __syncthreads();

    // ---- last block computes the loss (deterministic: wmin fully reduced) ----
    if (islast) {
        __threadfence();                             // acquire all blocks' mins
        int t = threadIdx.x;
        double ssum = 0.0;
        #pragma unroll 4
        for (int j = 0; j < BN / 256; ++j) {
            int i = t + j * 256;
            float mv = dec_f(wmin[i]);               // min over (d^2 - |q|^2)
            float d2 = fmaxf(mv + cand4[i].w, 0.0f); // + |q|^2, clamp
            float e  = sqrtf(d2) - 0.2f;
            ssum += (double)(e * e);
        }
        for (int off = 32; off; off >>= 1) ssum += __shfl_down(ssum, off);
        __shared__ double sh2[4];
        if (l == 0) sh2[w] = ssum;
        __syncthreads();
        if (t == 0)
            out[0] = (float)((sh2[0] + sh2[1] + sh2[2] + sh2[3]) / (double)BN);
    }
}

// ---------------- fallback (tiny workspace): fused single kernel ------------
__global__ __launch_bounds__(64) void k_single(const float* __restrict__ c,
                                               float* __restrict__ out) {
    __shared__ float sx[N], sy[N], sz[N];
    int blk = blockIdx.x;
    int qt  = blk & (N / 64 - 1);
    int b   = blk / (N / 64);
    const float* cb = c + (size_t)b * N * 3;
    int t = threadIdx.x;

    for (int k = t; k < N; k += 64) {
        sx[k] = cb[3 * k];
        sy[k] = cb[3 * k + 1];
        sz[k] = cb[3 * k + 2];
    }
    __syncthreads();

    int   qi = qt * 64 + t;
    float qx = sx[qi], qy = sy[qi], qz = sz[qi];
    const float INF = __uint_as_float(0x7F800000u);
    float m0 = INF, m1 = INF;
    for (int k = 0; k < N; k += 2) {
        float dx0 = qx - sx[k],     dy0 = qy - sy[k],     dz0 = qz - sz[k];
        float dx1 = qx - sx[k + 1], dy1 = qy - sy[k + 1], dz1 = qz - sz[k + 1];
        float d0 = dx0 * dx0 + dy0 * dy0 + dz0 * dz0;
        float d1 = dx1 * dx1 + dy1 * dy1 + dz1 * dz1;
        d0 = (k + 0 == qi) ? INF : d0;
        d1 = (k + 1 == qi) ? INF : d1;
        m0 = fminf(m0, d0);
        m1 = fminf(m1, d1);
    }
    float e = sqrtf(fminf(m0, m1)) - 0.2f;
    float v = e * e;
    for (int off = 32; off; off >>= 1) v += __shfl_down(v, off);
    if (t == 0) atomicAdd(out, v / (float)BN);
}

extern "C" void kernel_launch(void* const* d_in, const int* in_sizes, int n_in,
                              void* d_out, int out_size, void* d_ws, size_t ws_size,
                              hipStream_t stream) {
    const float* c   = (const float*)d_in[0];
    float*       out = (float*)d_out;

    const size_t off_cand = (size_t)BN * sizeof(unsigned);          // 131072
    const size_t off_cnt  = off_cand + (size_t)BN * sizeof(float4); // 655360
    if (ws_size >= off_cnt + sizeof(unsigned)) {
        unsigned* wmin    = (unsigned*)d_ws;
        float4*   cand4   = (float4*)((char*)d_ws + off_cand);
        unsigned* counter = (unsigned*)((char*)d_ws + off_cnt);
        k_init<<<BN / 256, 256, 0, stream>>>(c, wmin, cand4, counter);
        k_min<<<NBLK, 256, 0, stream>>>(c, cand4, wmin, counter, out);
    } else {
        hipMemsetAsync(d_out, 0, sizeof(float), stream);
        k_single<<<B * (N / 64), 64, 0, stream>>>(c, out);
    }
}

// Round 4
// 51.775 us; speedup vs baseline: 1.1192x; 1.1192x over previous
//
#include <hip/hip_runtime.h>
#include <hip/hip_bf16.h>

#define B 8
#define N 4096
#define BN (B * N)          // 32768 nodes total
#define NBLK 1024           // k_min grid: 8 b x 16 qc x 8 cc

// ---- order-preserving float <-> uint key (handles negative floats) ----
__device__ __forceinline__ unsigned enc_f(float f) {
    unsigned u = __float_as_uint(f);
    return u ^ (unsigned)(((int)u >> 31) | 0x80000000);
}
__device__ __forceinline__ float dec_f(unsigned k) {
    unsigned u = (k & 0x80000000u) ? (k ^ 0x80000000u) : ~k;
    return __uint_as_float(u);
}
#define ENC_INF 0xFF800000u   // enc_f(+inf)

// ---------------- init: wmin=enc(inf), transformed candidates, counter=0 ----
// cand4[i] = (-2x, -2y, -2z, |c|^2) so that
// d^2(q,c) - |q|^2 = fma(qx,cand.x, fma(qy,cand.y, fma(qz,cand.z, cand.w)))
__global__ __launch_bounds__(256) void k_init(const float* __restrict__ c,
                                              unsigned* __restrict__ wmin,
                                              float4* __restrict__ cand4,
                                              unsigned* __restrict__ counter) {
    int i = blockIdx.x * 256 + threadIdx.x;   // grid covers exactly BN
    float x = c[3 * i], y = c[3 * i + 1], z = c[3 * i + 2];
    wmin[i]  = ENC_INF;
    cand4[i] = make_float4(-2.0f * x, -2.0f * y, -2.0f * z,
                           x * x + y * y + z * z);
    if (i == 0) *counter = 0u;
}

// ---------------- main: min over v = d^2 - |q|^2, fused final loss ----------
// Block (256 thr = 4 waves): 256 queries x 512 candidates.
// Candidates staged in LDS (float4, broadcast ds_read_b128 in inner loop).
// Wave w owns the 128-cand sub-chunk [w*128, w*128+128).
// Thread: 4 consecutive queries in registers; 3 FMA + 1/2 min3 per pair.
__global__ __launch_bounds__(256) void k_min(const float* __restrict__ c,
                                             const float4* __restrict__ cand4,
                                             unsigned* __restrict__ wmin,
                                             unsigned* __restrict__ counter,
                                             float* __restrict__ out) {
    __shared__ float4 sc[512];        // 8 KB candidate tile
    __shared__ float4 shm[3][64];     // cross-wave reduce
    __shared__ int islast;

    int blk = blockIdx.x;
    int cc  = blk & 7;          // candidate super-chunk (512)
    int qc  = (blk >> 3) & 15;  // query chunk (256)
    int b   = blk >> 7;         // batch

    int w = __builtin_amdgcn_readfirstlane((int)(threadIdx.x >> 6));
    int l = threadIdx.x & 63;
    int t = threadIdx.x;

    const float* cb = c + (size_t)b * N * 3;
    int qbase = qc * 256;
    int cbase = cc * 512;

    // ---- stage candidate tile into LDS (coalesced float4) ----
    const float4* gc = cand4 + (size_t)b * N + cbase;
    sc[t]       = gc[t];
    sc[t + 256] = gc[t + 256];

    // this thread's 4 queries (48 contiguous bytes)
    const float4* q4p = (const float4*)(cb + 3 * qbase + 12 * l);
    float4 a0 = q4p[0], a1 = q4p[1], a2 = q4p[2];
    float qx0 = a0.x, qy0 = a0.y, qz0 = a0.z;
    float qx1 = a0.w, qy1 = a1.x, qz1 = a1.y;
    float qx2 = a1.z, qy2 = a1.w, qz2 = a2.x;
    float qx3 = a2.y, qy3 = a2.z, qz3 = a2.w;

    __syncthreads();

    const float INF = __uint_as_float(0x7F800000u);
    float m0 = INF, m1 = INF, m2 = INF, m3 = INF;

    int cstart = cbase + w * 128;            // this wave's global cand start
    const float4* wc = sc + w * 128;         // LDS base (uniform per wave)

    if ((unsigned)(cstart - qbase) >= 256u) {
        // off-diagonal: no self possible
        #pragma unroll 4
        for (int k = 0; k < 128; k += 2) {
            float4 u = wc[k], v = wc[k + 1];
            float va0 = fmaf(qx0, u.x, fmaf(qy0, u.y, fmaf(qz0, u.z, u.w)));
            float vb0 = fmaf(qx0, v.x, fmaf(qy0, v.y, fmaf(qz0, v.z, v.w)));
            float va1 = fmaf(qx1, u.x, fmaf(qy1, u.y, fmaf(qz1, u.z, u.w)));
            float vb1 = fmaf(qx1, v.x, fmaf(qy1, v.y, fmaf(qz1, v.z, v.w)));
            float va2 = fmaf(qx2, u.x, fmaf(qy2, u.y, fmaf(qz2, u.z, u.w)));
            float vb2 = fmaf(qx2, v.x, fmaf(qy2, v.y, fmaf(qz2, v.z, v.w)));
            float va3 = fmaf(qx3, u.x, fmaf(qy3, u.y, fmaf(qz3, u.z, u.w)));
            float vb3 = fmaf(qx3, v.x, fmaf(qy3, v.y, fmaf(qz3, v.z, v.w)));
            m0 = fminf(fminf(m0, va0), vb0);   // -> v_min3_f32
            m1 = fminf(fminf(m1, va1), vb1);
            m2 = fminf(fminf(m2, va2), vb2);
            m3 = fminf(fminf(m3, va3), vb3);
        }
    } else {
        // diagonal wave: query (4l+j) at global index qbase+4l+j; relative
        // self index within this 128-chunk is s+j where s = qbase+4l-cstart.
        int s = (l << 2) - (cstart - qbase);
        #pragma unroll 4
        for (int k = 0; k < 128; ++k) {
            float4 u = wc[k];
            float v0 = fmaf(qx0, u.x, fmaf(qy0, u.y, fmaf(qz0, u.z, u.w)));
            float v1 = fmaf(qx1, u.x, fmaf(qy1, u.y, fmaf(qz1, u.z, u.w)));
            float v2 = fmaf(qx2, u.x, fmaf(qy2, u.y, fmaf(qz2, u.z, u.w)));
            float v3 = fmaf(qx3, u.x, fmaf(qy3, u.y, fmaf(qz3, u.z, u.w)));
            v0 = (k == s + 0) ? INF : v0;
            v1 = (k == s + 1) ? INF : v1;
            v2 = (k == s + 2) ? INF : v2;
            v3 = (k == s + 3) ? INF : v3;
            m0 = fminf(m0, v0);
            m1 = fminf(m1, v1);
            m2 = fminf(m2, v2);
            m3 = fminf(m3, v3);
        }
    }

    // ---- cross-wave min reduce in LDS (all 4 waves share the 256 queries) ----
    if (w) shm[w - 1][l] = make_float4(m0, m1, m2, m3);
    __syncthreads();
    if (w == 0) {
        #pragma unroll
        for (int ww = 0; ww < 3; ++ww) {
            float4 v = shm[ww][l];
            m0 = fminf(m0, v.x); m1 = fminf(m1, v.y);
            m2 = fminf(m2, v.z); m3 = fminf(m3, v.w);
        }
        unsigned* wp = wmin + b * N + qbase + (l << 2);
        atomicMin(wp + 0, enc_f(m0));
        atomicMin(wp + 1, enc_f(m1));
        atomicMin(wp + 2, enc_f(m2));
        atomicMin(wp + 3, enc_f(m3));
        if (l == 0) {
            __threadfence();                         // release our mins
            unsigned old = atomicAdd(counter, 1u);
            islast = (old == NBLK - 1);
        }
    }
    __syncthreads();

    // ---- last block computes the loss (deterministic: wmin fully reduced) ----
    if (islast) {
        __threadfence();                             // acquire all blocks' mins
        double ssum = 0.0;
        #pragma unroll 4
        for (int j = 0; j < BN / 256; ++j) {
            int i = t + j * 256;
            float mv = dec_f(wmin[i]);               // min over (d^2 - |q|^2)
            float d2 = fmaxf(mv + cand4[i].w, 0.0f); // + |q|^2, clamp
            float e  = sqrtf(d2) - 0.2f;
            ssum += (double)(e * e);
        }
        for (int off = 32; off; off >>= 1) ssum += __shfl_down(ssum, off);
        __shared__ double sh2[4];
        if (l == 0) sh2[w] = ssum;
        __syncthreads();
        if (t == 0)
            out[0] = (float)((sh2[0] + sh2[1] + sh2[2] + sh2[3]) / (double)BN);
    }
}

// ---------------- fallback (tiny workspace): fused single kernel ------------
__global__ __launch_bounds__(64) void k_single(const float* __restrict__ c,
                                               float* __restrict__ out) {
    __shared__ float sx[N], sy[N], sz[N];
    int blk = blockIdx.x;
    int qt  = blk & (N / 64 - 1);
    int b   = blk / (N / 64);
    const float* cb = c + (size_t)b * N * 3;
    int t = threadIdx.x;

    for (int k = t; k < N; k += 64) {
        sx[k] = cb[3 * k];
        sy[k] = cb[3 * k + 1];
        sz[k] = cb[3 * k + 2];
    }
    __syncthreads();

    int   qi = qt * 64 + t;
    float qx = sx[qi], qy = sy[qi], qz = sz[qi];
    const float INF = __uint_as_float(0x7F800000u);
    float m0 = INF, m1 = INF;
    for (int k = 0; k < N; k += 2) {
        float dx0 = qx - sx[k],     dy0 = qy - sy[k],     dz0 = qz - sz[k];
        float dx1 = qx - sx[k + 1], dy1 = qy - sy[k + 1], dz1 = qz - sz[k + 1];
        float d0 = dx0 * dx0 + dy0 * dy0 + dz0 * dz0;
        float d1 = dx1 * dx1 + dy1 * dy1 + dz1 * dz1;
        d0 = (k + 0 == qi) ? INF : d0;
        d1 = (k + 1 == qi) ? INF : d1;
        m0 = fminf(m0, d0);
        m1 = fminf(m1, d1);
    }
    float e = sqrtf(fminf(m0, m1)) - 0.2f;
    float v = e * e;
    for (int off = 32; off; off >>= 1) v += __shfl_down(v, off);
    if (t == 0) atomicAdd(out, v / (float)BN);
}

extern "C" void kernel_launch(void* const* d_in, const int* in_sizes, int n_in,
                              void* d_out, int out_size, void* d_ws, size_t ws_size,
                              hipStream_t stream) {
    const float* c   = (const float*)d_in[0];
    float*       out = (float*)d_out;

    const size_t off_cand = (size_t)BN * sizeof(unsigned);          // 131072
    const size_t off_cnt  = off_cand + (size_t)BN * sizeof(float4); // 655360
    if (ws_size >= off_cnt + sizeof(unsigned)) {
        unsigned* wmin    = (unsigned*)d_ws;
        float4*   cand4   = (float4*)((char*)d_ws + off_cand);
        unsigned* counter = (unsigned*)((char*)d_ws + off_cnt);
        k_init<<<BN / 256, 256, 0, stream>>>(c, wmin, cand4, counter);
        k_min<<<NBLK, 256, 0, stream>>>(c, cand4, wmin, counter, out);
    } else {
        hipMemsetAsync(d_out, 0, sizeof(float), stream);
        k_single<<<B * (N / 64), 64, 0, stream>>>(c, out);
    }
}

// Round 5
// 27.718 us; speedup vs baseline: 2.0905x; 1.8679x over previous
//
#include <hip/hip_runtime.h>
#include <hip/hip_bf16.h>

#define B 8
#define N 4096
#define BN (B * N)          // 32768 nodes total
#define NBLK_MIN 512        // 8 b x 16 qc x 4 cc
#define NBLK_LOSS 32

// ---- order-preserving float <-> uint key (handles negative floats) ----
__device__ __forceinline__ unsigned enc_f(float f) {
    unsigned u = __float_as_uint(f);
    return u ^ (unsigned)(((int)u >> 31) | 0x80000000);
}
__device__ __forceinline__ float dec_f(unsigned k) {
    unsigned u = (k & 0x80000000u) ? (k ^ 0x80000000u) : ~k;
    return __uint_as_float(u);
}
#define ENC_INF 0xFF800000u   // enc_f(+inf)

// ---------------- init: wmin=enc(inf), transformed candidates ----------------
// cand4[i] = (-2x, -2y, -2z, |c|^2) so that
// d^2(q,c) - |q|^2 = fma(qx,cand.x, fma(qy,cand.y, fma(qz,cand.z, cand.w)))
__global__ __launch_bounds__(256) void k_init(const float* __restrict__ c,
                                              unsigned* __restrict__ wmin,
                                              float4* __restrict__ cand4) {
    int i = blockIdx.x * 256 + threadIdx.x;   // grid covers exactly BN
    float x = c[3 * i], y = c[3 * i + 1], z = c[3 * i + 2];
    wmin[i]  = ENC_INF;
    cand4[i] = make_float4(-2.0f * x, -2.0f * y, -2.0f * z,
                           x * x + y * y + z * z);
}

// ---------------- main: min over v = d^2 - |q|^2 ----------------------------
// Block (256 thr = 4 waves): 256 queries x 1024 candidates.
// Wave g owns a private 256-cand LDS slice (staged once, no barriers needed
// until the final cross-wave reduce). Thread: 4 consecutive queries.
// Per 2 candidates: 2 broadcast ds_read_b128 + 24 FMA + 4 min3 -> VALU-bound.
__global__ __launch_bounds__(256) void k_min(const float* __restrict__ c,
                                             const float4* __restrict__ cand4,
                                             unsigned* __restrict__ wmin) {
    __shared__ float4 sc[4][256];     // 16 KB: per-wave candidate slice
    __shared__ float4 shm[3][64];     // cross-wave reduce

    int blk = blockIdx.x;
    int cc  = blk & 3;          // candidate super-chunk (1024)
    int qc  = (blk >> 2) & 15;  // query chunk (256)
    int b   = blk >> 6;         // batch

    int w = __builtin_amdgcn_readfirstlane((int)(threadIdx.x >> 6));
    int l = threadIdx.x & 63;

    const float* cb = c + (size_t)b * N * 3;
    int qbase = qc * 256;
    int S     = cc * 1024 + w * 256;       // this wave's global cand start

    // ---- stage this wave's 256-cand slice (coalesced; wave-private) ----
    const float4* gc = cand4 + (size_t)b * N + S;
    float4 r0 = gc[l], r1 = gc[l + 64], r2 = gc[l + 128], r3 = gc[l + 192];

    // this thread's 4 queries (48 contiguous bytes)
    const float4* q4p = (const float4*)(cb + 3 * qbase + 12 * l);
    float4 a0 = q4p[0], a1 = q4p[1], a2 = q4p[2];
    float qx0 = a0.x, qy0 = a0.y, qz0 = a0.z;
    float qx1 = a0.w, qy1 = a1.x, qz1 = a1.y;
    float qx2 = a1.z, qy2 = a1.w, qz2 = a2.x;
    float qx3 = a2.y, qy3 = a2.z, qz3 = a2.w;

    sc[w][l]       = r0;
    sc[w][l + 64]  = r1;
    sc[w][l + 128] = r2;
    sc[w][l + 192] = r3;

    const float INF = __uint_as_float(0x7F800000u);
    float m0 = INF, m1 = INF, m2 = INF, m3 = INF;

    const float4* wc = sc[w];              // uniform per wave -> broadcast reads

    if (S != qbase) {
        // off-diagonal wave: no self possible
        #pragma unroll 4
        for (int k = 0; k < 256; k += 2) {
            float4 u = wc[k], v = wc[k + 1];
            float va0 = fmaf(qx0, u.x, fmaf(qy0, u.y, fmaf(qz0, u.z, u.w)));
            float vb0 = fmaf(qx0, v.x, fmaf(qy0, v.y, fmaf(qz0, v.z, v.w)));
            float va1 = fmaf(qx1, u.x, fmaf(qy1, u.y, fmaf(qz1, u.z, u.w)));
            float vb1 = fmaf(qx1, v.x, fmaf(qy1, v.y, fmaf(qz1, v.z, v.w)));
            float va2 = fmaf(qx2, u.x, fmaf(qy2, u.y, fmaf(qz2, u.z, u.w)));
            float vb2 = fmaf(qx2, v.x, fmaf(qy2, v.y, fmaf(qz2, v.z, v.w)));
            float va3 = fmaf(qx3, u.x, fmaf(qy3, u.y, fmaf(qz3, u.z, u.w)));
            float vb3 = fmaf(qx3, v.x, fmaf(qy3, v.y, fmaf(qz3, v.z, v.w)));
            m0 = fminf(fminf(m0, va0), vb0);   // -> v_min3_f32
            m1 = fminf(fminf(m1, va1), vb1);
            m2 = fminf(fminf(m2, va2), vb2);
            m3 = fminf(fminf(m3, va3), vb3);
        }
    } else {
        // diagonal wave: query 4l+j has relative self index 4l+j
        int s = l << 2;
        #pragma unroll 4
        for (int k = 0; k < 256; ++k) {
            float4 u = wc[k];
            float v0 = fmaf(qx0, u.x, fmaf(qy0, u.y, fmaf(qz0, u.z, u.w)));
            float v1 = fmaf(qx1, u.x, fmaf(qy1, u.y, fmaf(qz1, u.z, u.w)));
            float v2 = fmaf(qx2, u.x, fmaf(qy2, u.y, fmaf(qz2, u.z, u.w)));
            float v3 = fmaf(qx3, u.x, fmaf(qy3, u.y, fmaf(qz3, u.z, u.w)));
            v0 = (k == s + 0) ? INF : v0;
            v1 = (k == s + 1) ? INF : v1;
            v2 = (k == s + 2) ? INF : v2;
            v3 = (k == s + 3) ? INF : v3;
            m0 = fminf(m0, v0);
            m1 = fminf(m1, v1);
            m2 = fminf(m2, v2);
            m3 = fminf(m3, v3);
        }
    }

    // ---- cross-wave min reduce (all 4 waves share the same 256 queries) ----
    if (w) shm[w - 1][l] = make_float4(m0, m1, m2, m3);
    __syncthreads();
    if (w == 0) {
        #pragma unroll
        for (int ww = 0; ww < 3; ++ww) {
            float4 v = shm[ww][l];
            m0 = fminf(m0, v.x); m1 = fminf(m1, v.y);
            m2 = fminf(m2, v.z); m3 = fminf(m3, v.w);
        }
        unsigned* wp = wmin + b * N + qbase + (l << 2);
        atomicMin(wp + 0, enc_f(m0));
        atomicMin(wp + 1, enc_f(m1));
        atomicMin(wp + 2, enc_f(m2));
        atomicMin(wp + 3, enc_f(m3));
    }
}

// ---------------- loss stage 1: 32 block partials (no atomics) --------------
__global__ __launch_bounds__(256) void k_loss1(const unsigned* __restrict__ wmin,
                                               const float4* __restrict__ cand4,
                                               double* __restrict__ partials) {
    int t    = threadIdx.x;
    int base = blockIdx.x * 1024 + t * 4;      // 4 consecutive queries
    uint4 v  = *(const uint4*)(wmin + base);
    double s = 0.0;
    float mv, d2, e;
    mv = dec_f(v.x); d2 = fmaxf(mv + cand4[base + 0].w, 0.0f);
    e = sqrtf(d2) - 0.2f; s += (double)(e * e);
    mv = dec_f(v.y); d2 = fmaxf(mv + cand4[base + 1].w, 0.0f);
    e = sqrtf(d2) - 0.2f; s += (double)(e * e);
    mv = dec_f(v.z); d2 = fmaxf(mv + cand4[base + 2].w, 0.0f);
    e = sqrtf(d2) - 0.2f; s += (double)(e * e);
    mv = dec_f(v.w); d2 = fmaxf(mv + cand4[base + 3].w, 0.0f);
    e = sqrtf(d2) - 0.2f; s += (double)(e * e);

    for (int off = 32; off; off >>= 1) s += __shfl_down(s, off);
    __shared__ double sh[4];
    int wv = t >> 6, l = t & 63;
    if (l == 0) sh[wv] = s;
    __syncthreads();
    if (t == 0) partials[blockIdx.x] = sh[0] + sh[1] + sh[2] + sh[3];
}

// ---------------- loss stage 2: sum 32 partials, write scalar ---------------
__global__ __launch_bounds__(64) void k_loss2(const double* __restrict__ partials,
                                              float* __restrict__ out) {
    int l = threadIdx.x;
    double s = (l < NBLK_LOSS) ? partials[l] : 0.0;
    for (int off = 32; off; off >>= 1) s += __shfl_down(s, off);
    if (l == 0) out[0] = (float)(s / (double)BN);
}

// ---------------- fallback (tiny workspace): fused single kernel ------------
__global__ __launch_bounds__(64) void k_single(const float* __restrict__ c,
                                               float* __restrict__ out) {
    __shared__ float sx[N], sy[N], sz[N];
    int blk = blockIdx.x;
    int qt  = blk & (N / 64 - 1);
    int b   = blk / (N / 64);
    const float* cb = c + (size_t)b * N * 3;
    int t = threadIdx.x;

    for (int k = t; k < N; k += 64) {
        sx[k] = cb[3 * k];
        sy[k] = cb[3 * k + 1];
        sz[k] = cb[3 * k + 2];
    }
    __syncthreads();

    int   qi = qt * 64 + t;
    float qx = sx[qi], qy = sy[qi], qz = sz[qi];
    const float INF = __uint_as_float(0x7F800000u);
    float m0 = INF, m1 = INF;
    for (int k = 0; k < N; k += 2) {
        float dx0 = qx - sx[k],     dy0 = qy - sy[k],     dz0 = qz - sz[k];
        float dx1 = qx - sx[k + 1], dy1 = qy - sy[k + 1], dz1 = qz - sz[k + 1];
        float d0 = dx0 * dx0 + dy0 * dy0 + dz0 * dz0;
        float d1 = dx1 * dx1 + dy1 * dy1 + dz1 * dz1;
        d0 = (k + 0 == qi) ? INF : d0;
        d1 = (k + 1 == qi) ? INF : d1;
        m0 = fminf(m0, d0);
        m1 = fminf(m1, d1);
    }
    float e = sqrtf(fminf(m0, m1)) - 0.2f;
    float v = e * e;
    for (int off = 32; off; off >>= 1) v += __shfl_down(v, off);
    if (t == 0) atomicAdd(out, v / (float)BN);
}

extern "C" void kernel_launch(void* const* d_in, const int* in_sizes, int n_in,
                              void* d_out, int out_size, void* d_ws, size_t ws_size,
                              hipStream_t stream) {
    const float* c   = (const float*)d_in[0];
    float*       out = (float*)d_out;

    const size_t off_cand = (size_t)BN * sizeof(unsigned);           // 131072
    const size_t off_part = off_cand + (size_t)BN * sizeof(float4);  // 655360
    const size_t need     = off_part + NBLK_LOSS * sizeof(double);
    if (ws_size >= need) {
        unsigned* wmin     = (unsigned*)d_ws;
        float4*   cand4    = (float4*)((char*)d_ws + off_cand);
        double*   partials = (double*)((char*)d_ws + off_part);
        k_init <<<BN / 256, 256, 0, stream>>>(c, wmin, cand4);
        k_min  <<<NBLK_MIN, 256, 0, stream>>>(c, cand4, wmin);
        k_loss1<<<NBLK_LOSS, 256, 0, stream>>>(wmin, cand4, partials);
        k_loss2<<<1, 64, 0, stream>>>(partials, out);
    } else {
        hipMemsetAsync(d_out, 0, sizeof(float), stream);
        k_single<<<B * (N / 64), 64, 0, stream>>>(c, out);
    }
}

// Round 6
// 21.414 us; speedup vs baseline: 2.7059x; 1.2944x over previous
//
#include <hip/hip_runtime.h>
#include <hip/hip_bf16.h>

#define B 8
#define N 4096
#define BN (B * N)            // 32768 nodes
#define NCHUNK 128            // B * 16 query chunks of 256
#define NBLK_MAIN 512         // 8 b x 16 qc x 4 cc
#define NBLK_DIAG 128         // 8 b x 16 qc
#define NBLK_MIN (NBLK_MAIN + NBLK_DIAG)

typedef float f32x2 __attribute__((ext_vector_type(2)));

__device__ __forceinline__ f32x2 pkfma(f32x2 a, f32x2 b, f32x2 c) {
    f32x2 d;
    asm("v_pk_fma_f32 %0, %1, %2, %3" : "=v"(d) : "v"(a), "v"(b), "v"(c));
    return d;
}
__device__ __forceinline__ float min3f(float a, float b, float c) {
    float d;
    asm("v_min3_f32 %0, %1, %2, %3" : "=v"(d) : "v"(a), "v"(b), "v"(c));
    return d;
}

// ---------------- k_min: block-partial min of v = d^2 - |q|^2 ---------------
// Main blocks (0..511): (b, qc, cc). 4 waves; wave w owns candidate chunk
//   cc*4+w (256 cands) in packed-pair SoA LDS; SKIPS if it equals qc (self
//   chunk -> handled by diag blocks). 4 queries/thread, v_pk_fma_f32 inner.
// Diag blocks (512..639): (b, qc). wave w owns 64 cands of chunk qc, scalar
//   path with self-mask.
// Epilogue: cross-wave min reduce, plain store to wpart[(b*16+qc)*5 + slot].
__global__ __launch_bounds__(256) void k_min(const float* __restrict__ c,
                                             float* __restrict__ wpart) {
    __shared__ f32x2 X2[4][128], Y2[4][128], Z2[4][128], W2[4][128]; // 16 KB
    __shared__ float4 scD[4][64];                                    // 4 KB
    __shared__ float4 shm[3][64];                                    // 3 KB

    int w = __builtin_amdgcn_readfirstlane((int)(threadIdx.x >> 6));
    int l = threadIdx.x & 63;

    int blk = blockIdx.x;
    bool isdiag = (blk >= NBLK_MAIN);

    int b, qc, cc = 0;
    if (!isdiag) {
        cc = blk & 3;
        qc = (blk >> 2) & 15;
        b  = blk >> 6;
    } else {
        int idx = blk - NBLK_MAIN;
        qc = idx & 15;
        b  = idx >> 4;
    }

    const float* cb = c + (size_t)b * N * 3;
    int qbase = qc * 256;

    // ---- load this thread's 4 queries (48 contiguous bytes) ----
    const float4* q4p = (const float4*)(cb + 3 * qbase + 12 * l);
    float4 a0 = q4p[0], a1 = q4p[1], a2 = q4p[2];
    float qx0 = a0.x, qy0 = a0.y, qz0 = a0.z;
    float qx1 = a0.w, qy1 = a1.x, qz1 = a1.y;
    float qx2 = a1.z, qy2 = a1.w, qz2 = a2.x;
    float qx3 = a2.y, qy3 = a2.z, qz3 = a2.w;

    const float INF = __uint_as_float(0x7F800000u);
    float m0 = INF, m1 = INF, m2 = INF, m3 = INF;
    int slot;

    if (!isdiag) {
        slot = cc;
        int chunk = cc * 4 + w;               // this wave's candidate chunk
        if (chunk != qc) {
            // ---- stage 256 cands -> packed-pair SoA (wave-private) ----
            const float* gcand = cb + 3 * (chunk << 8);
            const float4* g4 = (const float4*)(gcand + 12 * l); // cands 4l..4l+3
            float4 c0 = g4[0], c1 = g4[1], c2 = g4[2];
            float Ax = c0.x, Ay = c0.y, Az = c0.z;
            float Bx = c0.w, By = c1.x, Bz = c1.y;
            float Cx = c1.z, Cy = c1.w, Cz = c2.x;
            float Dx = c2.y, Dy = c2.z, Dz = c2.w;
            float nA = fmaf(Az, Az, fmaf(Ay, Ay, Ax * Ax));
            float nB = fmaf(Bz, Bz, fmaf(By, By, Bx * Bx));
            float nC = fmaf(Cz, Cz, fmaf(Cy, Cy, Cx * Cx));
            float nD = fmaf(Dz, Dz, fmaf(Dy, Dy, Dx * Dx));
            *(float4*)(&X2[w][2 * l]) = make_float4(-2.f * Ax, -2.f * Bx, -2.f * Cx, -2.f * Dx);
            *(float4*)(&Y2[w][2 * l]) = make_float4(-2.f * Ay, -2.f * By, -2.f * Cy, -2.f * Dy);
            *(float4*)(&Z2[w][2 * l]) = make_float4(-2.f * Az, -2.f * Bz, -2.f * Cz, -2.f * Dz);
            *(float4*)(&W2[w][2 * l]) = make_float4(nA, nB, nC, nD);

            f32x2 qX0 = {qx0, qx0}, qY0 = {qy0, qy0}, qZ0 = {qz0, qz0};
            f32x2 qX1 = {qx1, qx1}, qY1 = {qy1, qy1}, qZ1 = {qz1, qz1};
            f32x2 qX2 = {qx2, qx2}, qY2 = {qy2, qy2}, qZ2 = {qz2, qz2};
            f32x2 qX3 = {qx3, qx3}, qY3 = {qy3, qy3}, qZ3 = {qz3, qz3};

            const f32x2* Xw = X2[w];
            const f32x2* Yw = Y2[w];
            const f32x2* Zw = Z2[w];
            const f32x2* Ww = W2[w];

            // wave-private LDS: no barrier needed (compiler inserts lgkmcnt)
            #pragma unroll 2
            for (int p = 0; p < 128; p += 2) {
                float4 xx = *(const float4*)(Xw + p);
                float4 yy = *(const float4*)(Yw + p);
                float4 zz = *(const float4*)(Zw + p);
                float4 ww = *(const float4*)(Ww + p);
                f32x2 xlo = {xx.x, xx.y}, xhi = {xx.z, xx.w};
                f32x2 ylo = {yy.x, yy.y}, yhi = {yy.z, yy.w};
                f32x2 zlo = {zz.x, zz.y}, zhi = {zz.z, zz.w};
                f32x2 wlo = {ww.x, ww.y}, whi = {ww.z, ww.w};

                f32x2 t0 = pkfma(qZ0, zlo, wlo); t0 = pkfma(qY0, ylo, t0); t0 = pkfma(qX0, xlo, t0);
                m0 = min3f(m0, t0.x, t0.y);
                f32x2 u0 = pkfma(qZ0, zhi, whi); u0 = pkfma(qY0, yhi, u0); u0 = pkfma(qX0, xhi, u0);
                m0 = min3f(m0, u0.x, u0.y);

                f32x2 t1 = pkfma(qZ1, zlo, wlo); t1 = pkfma(qY1, ylo, t1); t1 = pkfma(qX1, xlo, t1);
                m1 = min3f(m1, t1.x, t1.y);
                f32x2 u1 = pkfma(qZ1, zhi, whi); u1 = pkfma(qY1, yhi, u1); u1 = pkfma(qX1, xhi, u1);
                m1 = min3f(m1, u1.x, u1.y);

                f32x2 t2 = pkfma(qZ2, zlo, wlo); t2 = pkfma(qY2, ylo, t2); t2 = pkfma(qX2, xlo, t2);
                m2 = min3f(m2, t2.x, t2.y);
                f32x2 u2 = pkfma(qZ2, zhi, whi); u2 = pkfma(qY2, yhi, u2); u2 = pkfma(qX2, xhi, u2);
                m2 = min3f(m2, u2.x, u2.y);

                f32x2 t3 = pkfma(qZ3, zlo, wlo); t3 = pkfma(qY3, ylo, t3); t3 = pkfma(qX3, xlo, t3);
                m3 = min3f(m3, t3.x, t3.y);
                f32x2 u3 = pkfma(qZ3, zhi, whi); u3 = pkfma(qY3, yhi, u3); u3 = pkfma(qX3, xhi, u3);
                m3 = min3f(m3, u3.x, u3.y);
            }
        }
        // skipped wave keeps m = INF
    } else {
        slot = 4;
        // ---- diag: wave w owns 64 cands [qbase + w*64, +64), self-masked ----
        int ci = qbase + w * 64 + l;          // lane's candidate (global in batch)
        float x = cb[3 * ci], y = cb[3 * ci + 1], z = cb[3 * ci + 2];
        float nrm = fmaf(z, z, fmaf(y, y, x * x));
        scD[w][l] = make_float4(-2.f * x, -2.f * y, -2.f * z, nrm);

        int s = (l << 2) - (w << 6);          // self rel idx for query j is s+j
        const float4* wc = scD[w];            // wave-private, broadcast reads
        #pragma unroll 4
        for (int k = 0; k < 64; ++k) {
            float4 u = wc[k];
            float v0 = fmaf(qx0, u.x, fmaf(qy0, u.y, fmaf(qz0, u.z, u.w)));
            float v1 = fmaf(qx1, u.x, fmaf(qy1, u.y, fmaf(qz1, u.z, u.w)));
            float v2 = fmaf(qx2, u.x, fmaf(qy2, u.y, fmaf(qz2, u.z, u.w)));
            float v3 = fmaf(qx3, u.x, fmaf(qy3, u.y, fmaf(qz3, u.z, u.w)));
            v0 = (k == s + 0) ? INF : v0;
            v1 = (k == s + 1) ? INF : v1;
            v2 = (k == s + 2) ? INF : v2;
            v3 = (k == s + 3) ? INF : v3;
            m0 = fminf(m0, v0);
            m1 = fminf(m1, v1);
            m2 = fminf(m2, v2);
            m3 = fminf(m3, v3);
        }
    }

    // ---- cross-wave min reduce; plain store of block partial ----
    if (w) shm[w - 1][l] = make_float4(m0, m1, m2, m3);
    __syncthreads();
    if (w == 0) {
        #pragma unroll
        for (int ww = 0; ww < 3; ++ww) {
            float4 v = shm[ww][l];
            m0 = fminf(m0, v.x); m1 = fminf(m1, v.y);
            m2 = fminf(m2, v.z); m3 = fminf(m3, v.w);
        }
        size_t widx = ((size_t)(b * 16 + qc) * 5 + slot) * 256 + (l << 2);
        *(float4*)(wpart + widx) = make_float4(m0, m1, m2, m3);
    }
}

// ---------------- loss stage 1: per-chunk partial (no atomics) --------------
__global__ __launch_bounds__(256) void k_loss1(const float* __restrict__ c,
                                               const float* __restrict__ wpart,
                                               double* __restrict__ partials) {
    int chunk = blockIdx.x;                   // 0..127  == b*16+qc
    int t = threadIdx.x;
    const float* wp = wpart + (size_t)chunk * 5 * 256 + t;
    float m = wp[0];
    m = fminf(m, wp[256]);
    m = fminf(m, wp[512]);
    m = fminf(m, wp[768]);
    m = fminf(m, wp[1024]);

    int i = chunk * 256 + t;                  // global node index
    float x = c[3 * i], y = c[3 * i + 1], z = c[3 * i + 2];
    float nrm = fmaf(z, z, fmaf(y, y, x * x));
    float d2 = fmaxf(m + nrm, 0.0f);
    float e  = sqrtf(d2) - 0.2f;
    double s = (double)(e * e);

    for (int off = 32; off; off >>= 1) s += __shfl_down(s, off);
    __shared__ double sh[4];
    int wv = t >> 6, l = t & 63;
    if (l == 0) sh[wv] = s;
    __syncthreads();
    if (t == 0) partials[chunk] = sh[0] + sh[1] + sh[2] + sh[3];
}

// ---------------- loss stage 2: fold 128 partials -> scalar -----------------
__global__ __launch_bounds__(128) void k_loss2(const double* __restrict__ partials,
                                               float* __restrict__ out) {
    int t = threadIdx.x;
    double s = partials[t];
    for (int off = 32; off; off >>= 1) s += __shfl_down(s, off);
    __shared__ double sh[2];
    if ((t & 63) == 0) sh[t >> 6] = s;
    __syncthreads();
    if (t == 0) out[0] = (float)((sh[0] + sh[1]) / (double)BN);
}

// ---------------- fallback (tiny workspace): fused single kernel ------------
__global__ __launch_bounds__(64) void k_single(const float* __restrict__ c,
                                               float* __restrict__ out) {
    __shared__ float sx[N], sy[N], sz[N];
    int blk = blockIdx.x;
    int qt  = blk & (N / 64 - 1);
    int b   = blk / (N / 64);
    const float* cb = c + (size_t)b * N * 3;
    int t = threadIdx.x;

    for (int k = t; k < N; k += 64) {
        sx[k] = cb[3 * k];
        sy[k] = cb[3 * k + 1];
        sz[k] = cb[3 * k + 2];
    }
    __syncthreads();

    int   qi = qt * 64 + t;
    float qx = sx[qi], qy = sy[qi], qz = sz[qi];
    const float INF = __uint_as_float(0x7F800000u);
    float m0 = INF, m1 = INF;
    for (int k = 0; k < N; k += 2) {
        float dx0 = qx - sx[k],     dy0 = qy - sy[k],     dz0 = qz - sz[k];
        float dx1 = qx - sx[k + 1], dy1 = qy - sy[k + 1], dz1 = qz - sz[k + 1];
        float d0 = dx0 * dx0 + dy0 * dy0 + dz0 * dz0;
        float d1 = dx1 * dx1 + dy1 * dy1 + dz1 * dz1;
        d0 = (k + 0 == qi) ? INF : d0;
        d1 = (k + 1 == qi) ? INF : d1;
        m0 = fminf(m0, d0);
        m1 = fminf(m1, d1);
    }
    float e = sqrtf(fminf(m0, m1)) - 0.2f;
    float v = e * e;
    for (int off = 32; off; off >>= 1) v += __shfl_down(v, off);
    if (t == 0) atomicAdd(out, v / (float)BN);
}

extern "C" void kernel_launch(void* const* d_in, const int* in_sizes, int n_in,
                              void* d_out, int out_size, void* d_ws, size_t ws_size,
                              hipStream_t stream) {
    const float* c   = (const float*)d_in[0];
    float*       out = (float*)d_out;

    const size_t off_part = (size_t)NCHUNK * 5 * 256 * sizeof(float); // 655360
    const size_t need     = off_part + NCHUNK * sizeof(double);       // 656384
    if (ws_size >= need) {
        float*  wpart    = (float*)d_ws;
        double* partials = (double*)((char*)d_ws + off_part);
        k_min  <<<NBLK_MIN, 256, 0, stream>>>(c, wpart);
        k_loss1<<<NCHUNK, 256, 0, stream>>>(c, wpart, partials);
        k_loss2<<<1, 128, 0, stream>>>(partials, out);
    } else {
        hipMemsetAsync(d_out, 0, sizeof(float), stream);
        k_single<<<B * (N / 64), 64, 0, stream>>>(c, out);
    }
}

// Round 7
// 21.360 us; speedup vs baseline: 2.7127x; 1.0025x over previous
//
#include <hip/hip_runtime.h>
#include <hip/hip_bf16.h>

#define B 8
#define N 4096
#define BN (B * N)            // 32768 nodes
#define NCHUNK 128            // B * 16 query chunks of 256
#define NSLOT 9               // 8 main cc slots + 1 diag
#define NBLK_MAIN 1024        // 8 b x 16 qc x 8 cc
#define NBLK_DIAG 128         // 8 b x 16 qc
#define NBLK_MIN (NBLK_MAIN + NBLK_DIAG)

typedef float f32x2 __attribute__((ext_vector_type(2)));

__device__ __forceinline__ f32x2 pkfma(f32x2 a, f32x2 b, f32x2 c) {
    f32x2 d;
    asm("v_pk_fma_f32 %0, %1, %2, %3" : "=v"(d) : "v"(a), "v"(b), "v"(c));
    return d;
}
__device__ __forceinline__ float min3f(float a, float b, float c) {
    float d;
    asm("v_min3_f32 %0, %1, %2, %3" : "=v"(d) : "v"(a), "v"(b), "v"(c));
    return d;
}

// ---------------- k_min: block-partial min of v = d^2 - |q|^2 ---------------
// Main blocks (0..1023): (b, qc, cc). Block = 256 queries x 512 cands.
//   Wave w owns 128-cand chunk idx128 = cc*4+w (pair-SoA in LDS, 2 cands/lane
//   staging); SKIPS if idx128 overlaps the query chunk (diag handles it).
//   4 queries/thread, v_pk_fma_f32 + v_min3_f32 inner loop (2 inst/pair).
// Diag blocks (1024..1151): (b, qc). Wave w owns 64 cands of chunk qc,
//   scalar path with self-mask.
// Epilogue: cross-wave min reduce, plain store to wpart[(b*16+qc)*9 + slot].
__global__ __launch_bounds__(256) void k_min(const float* __restrict__ c,
                                             float* __restrict__ wpart) {
    __shared__ f32x2 X2[4][64], Y2[4][64], Z2[4][64], W2[4][64];  // 8 KB
    __shared__ float4 scD[4][64];                                 // 4 KB
    __shared__ float4 shm[3][64];                                 // 3 KB

    int w = __builtin_amdgcn_readfirstlane((int)(threadIdx.x >> 6));
    int l = threadIdx.x & 63;

    int blk = blockIdx.x;
    bool isdiag = (blk >= NBLK_MAIN);

    int b, qc, cc = 0;
    if (!isdiag) {
        cc = blk & 7;
        qc = (blk >> 3) & 15;
        b  = blk >> 7;
    } else {
        int idx = blk - NBLK_MAIN;
        qc = idx & 15;
        b  = idx >> 4;
    }

    const float* cb = c + (size_t)b * N * 3;
    int qbase = qc * 256;

    // ---- load this thread's 4 queries (48 contiguous bytes, 16B aligned) ----
    const float4* q4p = (const float4*)(cb + 3 * qbase + 12 * l);
    float4 a0 = q4p[0], a1 = q4p[1], a2 = q4p[2];
    float qx0 = a0.x, qy0 = a0.y, qz0 = a0.z;
    float qx1 = a0.w, qy1 = a1.x, qz1 = a1.y;
    float qx2 = a1.z, qy2 = a1.w, qz2 = a2.x;
    float qx3 = a2.y, qy3 = a2.z, qz3 = a2.w;

    const float INF = __uint_as_float(0x7F800000u);
    float m0 = INF, m1 = INF, m2 = INF, m3 = INF;
    int slot;

    if (!isdiag) {
        slot = cc;
        int idx128 = cc * 4 + w;              // this wave's 128-cand chunk
        if ((idx128 >> 1) != qc) {            // skip chunks overlapping queries
            // ---- stage 128 cands (2/lane) -> packed-pair SoA ----
            const float2* g2 = (const float2*)(cb + 3 * (idx128 << 7)) + 3 * l;
            float2 e0 = g2[0], e1 = g2[1], e2 = g2[2];
            // cand A = (e0.x, e0.y, e1.x), cand B = (e1.y, e2.x, e2.y)
            float nA = fmaf(e1.x, e1.x, fmaf(e0.y, e0.y, e0.x * e0.x));
            float nB = fmaf(e2.y, e2.y, fmaf(e2.x, e2.x, e1.y * e1.y));
            X2[w][l] = (f32x2){-2.f * e0.x, -2.f * e1.y};
            Y2[w][l] = (f32x2){-2.f * e0.y, -2.f * e2.x};
            Z2[w][l] = (f32x2){-2.f * e1.x, -2.f * e2.y};
            W2[w][l] = (f32x2){nA, nB};

            f32x2 qX0 = {qx0, qx0}, qY0 = {qy0, qy0}, qZ0 = {qz0, qz0};
            f32x2 qX1 = {qx1, qx1}, qY1 = {qy1, qy1}, qZ1 = {qz1, qz1};
            f32x2 qX2 = {qx2, qx2}, qY2 = {qy2, qy2}, qZ2 = {qz2, qz2};
            f32x2 qX3 = {qx3, qx3}, qY3 = {qy3, qy3}, qZ3 = {qz3, qz3};

            const f32x2* Xw = X2[w];
            const f32x2* Yw = Y2[w];
            const f32x2* Zw = Z2[w];
            const f32x2* Ww = W2[w];

            // wave-private LDS: no barrier needed (compiler inserts lgkmcnt)
            #pragma unroll 4
            for (int p = 0; p < 64; p += 2) {
                float4 xx = *(const float4*)(Xw + p);   // pairs p, p+1
                float4 yy = *(const float4*)(Yw + p);
                float4 zz = *(const float4*)(Zw + p);
                float4 ww = *(const float4*)(Ww + p);
                f32x2 xlo = {xx.x, xx.y}, xhi = {xx.z, xx.w};
                f32x2 ylo = {yy.x, yy.y}, yhi = {yy.z, yy.w};
                f32x2 zlo = {zz.x, zz.y}, zhi = {zz.z, zz.w};
                f32x2 wlo = {ww.x, ww.y}, whi = {ww.z, ww.w};

                f32x2 t0 = pkfma(qZ0, zlo, wlo); t0 = pkfma(qY0, ylo, t0); t0 = pkfma(qX0, xlo, t0);
                m0 = min3f(m0, t0.x, t0.y);
                f32x2 u0 = pkfma(qZ0, zhi, whi); u0 = pkfma(qY0, yhi, u0); u0 = pkfma(qX0, xhi, u0);
                m0 = min3f(m0, u0.x, u0.y);

                f32x2 t1 = pkfma(qZ1, zlo, wlo); t1 = pkfma(qY1, ylo, t1); t1 = pkfma(qX1, xlo, t1);
                m1 = min3f(m1, t1.x, t1.y);
                f32x2 u1 = pkfma(qZ1, zhi, whi); u1 = pkfma(qY1, yhi, u1); u1 = pkfma(qX1, xhi, u1);
                m1 = min3f(m1, u1.x, u1.y);

                f32x2 t2 = pkfma(qZ2, zlo, wlo); t2 = pkfma(qY2, ylo, t2); t2 = pkfma(qX2, xlo, t2);
                m2 = min3f(m2, t2.x, t2.y);
                f32x2 u2 = pkfma(qZ2, zhi, whi); u2 = pkfma(qY2, yhi, u2); u2 = pkfma(qX2, xhi, u2);
                m2 = min3f(m2, u2.x, u2.y);

                f32x2 t3 = pkfma(qZ3, zlo, wlo); t3 = pkfma(qY3, ylo, t3); t3 = pkfma(qX3, xlo, t3);
                m3 = min3f(m3, t3.x, t3.y);
                f32x2 u3 = pkfma(qZ3, zhi, whi); u3 = pkfma(qY3, yhi, u3); u3 = pkfma(qX3, xhi, u3);
                m3 = min3f(m3, u3.x, u3.y);
            }
        }
        // skipped wave keeps m = INF
    } else {
        slot = 8;
        // ---- diag: wave w owns 64 cands [qbase + w*64, +64), self-masked ----
        int ci = qbase + w * 64 + l;          // lane's candidate (global in batch)
        float x = cb[3 * ci], y = cb[3 * ci + 1], z = cb[3 * ci + 2];
        float nrm = fmaf(z, z, fmaf(y, y, x * x));
        scD[w][l] = make_float4(-2.f * x, -2.f * y, -2.f * z, nrm);

        int s = (l << 2) - (w << 6);          // self rel idx for query j is s+j
        const float4* wc = scD[w];            // wave-private, broadcast reads
        #pragma unroll 4
        for (int k = 0; k < 64; ++k) {
            float4 u = wc[k];
            float v0 = fmaf(qx0, u.x, fmaf(qy0, u.y, fmaf(qz0, u.z, u.w)));
            float v1 = fmaf(qx1, u.x, fmaf(qy1, u.y, fmaf(qz1, u.z, u.w)));
            float v2 = fmaf(qx2, u.x, fmaf(qy2, u.y, fmaf(qz2, u.z, u.w)));
            float v3 = fmaf(qx3, u.x, fmaf(qy3, u.y, fmaf(qz3, u.z, u.w)));
            v0 = (k == s + 0) ? INF : v0;
            v1 = (k == s + 1) ? INF : v1;
            v2 = (k == s + 2) ? INF : v2;
            v3 = (k == s + 3) ? INF : v3;
            m0 = fminf(m0, v0);
            m1 = fminf(m1, v1);
            m2 = fminf(m2, v2);
            m3 = fminf(m3, v3);
        }
    }

    // ---- cross-wave min reduce; plain store of block partial ----
    if (w) shm[w - 1][l] = make_float4(m0, m1, m2, m3);
    __syncthreads();
    if (w == 0) {
        #pragma unroll
        for (int ww = 0; ww < 3; ++ww) {
            float4 v = shm[ww][l];
            m0 = fminf(m0, v.x); m1 = fminf(m1, v.y);
            m2 = fminf(m2, v.z); m3 = fminf(m3, v.w);
        }
        size_t widx = ((size_t)(b * 16 + qc) * NSLOT + slot) * 256 + (l << 2);
        *(float4*)(wpart + widx) = make_float4(m0, m1, m2, m3);
    }
}

// ---------------- loss stage 1: per-chunk partial (no atomics) --------------
__global__ __launch_bounds__(256) void k_loss1(const float* __restrict__ c,
                                               const float* __restrict__ wpart,
                                               double* __restrict__ partials) {
    int chunk = blockIdx.x;                   // 0..127  == b*16+qc
    int t = threadIdx.x;
    const float* wp = wpart + (size_t)chunk * NSLOT * 256 + t;
    float m = wp[0];
    #pragma unroll
    for (int s = 1; s < NSLOT; ++s) m = fminf(m, wp[s * 256]);

    int i = chunk * 256 + t;                  // global node index
    float x = c[3 * i], y = c[3 * i + 1], z = c[3 * i + 2];
    float nrm = fmaf(z, z, fmaf(y, y, x * x));
    float d2 = fmaxf(m + nrm, 0.0f);
    float e  = sqrtf(d2) - 0.2f;
    double s = (double)(e * e);

    for (int off = 32; off; off >>= 1) s += __shfl_down(s, off);
    __shared__ double sh[4];
    int wv = t >> 6, l = t & 63;
    if (l == 0) sh[wv] = s;
    __syncthreads();
    if (t == 0) partials[chunk] = sh[0] + sh[1] + sh[2] + sh[3];
}

// ---------------- loss stage 2: fold 128 partials -> scalar -----------------
__global__ __launch_bounds__(128) void k_loss2(const double* __restrict__ partials,
                                               float* __restrict__ out) {
    int t = threadIdx.x;
    double s = partials[t];
    for (int off = 32; off; off >>= 1) s += __shfl_down(s, off);
    __shared__ double sh[2];
    if ((t & 63) == 0) sh[t >> 6] = s;
    __syncthreads();
    if (t == 0) out[0] = (float)((sh[0] + sh[1]) / (double)BN);
}

// ---------------- fallback (tiny workspace): fused single kernel ------------
__global__ __launch_bounds__(64) void k_single(const float* __restrict__ c,
                                               float* __restrict__ out) {
    __shared__ float sx[N], sy[N], sz[N];
    int blk = blockIdx.x;
    int qt  = blk & (N / 64 - 1);
    int b   = blk / (N / 64);
    const float* cb = c + (size_t)b * N * 3;
    int t = threadIdx.x;

    for (int k = t; k < N; k += 64) {
        sx[k] = cb[3 * k];
        sy[k] = cb[3 * k + 1];
        sz[k] = cb[3 * k + 2];
    }
    __syncthreads();

    int   qi = qt * 64 + t;
    float qx = sx[qi], qy = sy[qi], qz = sz[qi];
    const float INF = __uint_as_float(0x7F800000u);
    float m0 = INF, m1 = INF;
    for (int k = 0; k < N; k += 2) {
        float dx0 = qx - sx[k],     dy0 = qy - sy[k],     dz0 = qz - sz[k];
        float dx1 = qx - sx[k + 1], dy1 = qy - sy[k + 1], dz1 = qz - sz[k + 1];
        float d0 = dx0 * dx0 + dy0 * dy0 + dz0 * dz0;
        float d1 = dx1 * dx1 + dy1 * dy1 + dz1 * dz1;
        d0 = (k + 0 == qi) ? INF : d0;
        d1 = (k + 1 == qi) ? INF : d1;
        m0 = fminf(m0, d0);
        m1 = fminf(m1, d1);
    }
    float e = sqrtf(fminf(m0, m1)) - 0.2f;
    float v = e * e;
    for (int off = 32; off; off >>= 1) v += __shfl_down(v, off);
    if (t == 0) atomicAdd(out, v / (float)BN);
}

extern "C" void kernel_launch(void* const* d_in, const int* in_sizes, int n_in,
                              void* d_out, int out_size, void* d_ws, size_t ws_size,
                              hipStream_t stream) {
    const float* c   = (const float*)d_in[0];
    float*       out = (float*)d_out;

    const size_t off_part = (size_t)NCHUNK * NSLOT * 256 * sizeof(float);
    const size_t need     = off_part + NCHUNK * sizeof(double);
    if (ws_size >= need) {
        float*  wpart    = (float*)d_ws;
        double* partials = (double*)((char*)d_ws + off_part);
        k_min  <<<NBLK_MIN, 256, 0, stream>>>(c, wpart);
        k_loss1<<<NCHUNK, 256, 0, stream>>>(c, wpart, partials);
        k_loss2<<<1, 128, 0, stream>>>(partials, out);
    } else {
        hipMemsetAsync(d_out, 0, sizeof(float), stream);
        k_single<<<B * (N / 64), 64, 0, stream>>>(c, out);
    }
}